// Round 13
// baseline (200.967 us; speedup 1.0000x reference)
//
#include <hip/hip_runtime.h>

#define N_NODES 50000
#define E_EDGES 640000
#define F 128

typedef __attribute__((ext_vector_type(8))) short short8;
typedef __attribute__((ext_vector_type(4))) float f32x4;

// -------- workspace layout (bytes) --------
#define DEG_OFF 0            // N int32
#define OFF_OFF 200704       // N+1 int32
#define CUR_OFF 401408       // N int32
#define BSUM_OFF 601600      // 196 int32
#define WF_OFF 603648        // 32768 bf16 (64 KB) W fragments
#define SRC_OFF 734720       // E int32 -> ends 3,294,720
#define XBF_OFF 3294720      // N*F bf16 (12.8 MB)
#define MBF_OFF 16094720     // N*F bf16 (12.8 MB)
#define WS_NEED_FULL 28894720ULL

// fused fill|wprep|xcast block ranges (fill first: it's the critical path)
#define FILL_BLKS 2048
#define WPREP_BLKS 16
#define XCAST_BLKS 3125      // 3125*256*8 == N*F exactly
#define FXW_GRID (FILL_BLKS + WPREP_BLKS + XCAST_BLKS)

__device__ __forceinline__ unsigned short f2bf(float f) {
    unsigned int u = __builtin_bit_cast(unsigned int, f);
    u += 0x7FFFu + ((u >> 16) & 1u);  // round-to-nearest-even
    return (unsigned short)(u >> 16);
}
__device__ __forceinline__ float bfhi2f(unsigned int hi16) {  // bits 31:16
    return __builtin_bit_cast(float, hi16 & 0xFFFF0000u);
}

// -------- Kernel 1: in-degree histogram --------
__global__ __launch_bounds__(256) void gnn_hist(const int* __restrict__ ei,
                                                int* __restrict__ deg) {
    const int i = blockIdx.x * blockDim.x + threadIdx.x;
    const int stride = gridDim.x * blockDim.x;
    for (int e = i; e < E_EDGES; e += stride)
        atomicAdd(&deg[ei[E_EDGES + e]], 1);
}

// -------- Kernel 2a: per-block local scan (196 blocks x 256) --------
__global__ __launch_bounds__(256) void gnn_scan_a(const int* __restrict__ deg,
                                                  int* __restrict__ off,
                                                  int* __restrict__ bsum) {
    __shared__ int s[256];
    const int t = threadIdx.x;
    const int i = blockIdx.x * 256 + t;
    const int v = (i < N_NODES) ? deg[i] : 0;
    s[t] = v;
    __syncthreads();
    for (int d = 1; d < 256; d <<= 1) {
        const int u = (t >= d) ? s[t - d] : 0;
        __syncthreads();
        s[t] += u;
        __syncthreads();
    }
    if (i < N_NODES) off[i] = s[t] - v;
    if (t == 255) bsum[blockIdx.x] = s[255];
}

// -------- Kernel 2b: merged scan-of-sums + apply (196 blocks) --------
__global__ __launch_bounds__(256) void gnn_scan2(const int* __restrict__ bsum,
                                                 int* __restrict__ off,
                                                 int* __restrict__ cur) {
    __shared__ int s[256];
    const int t = threadIdx.x;
    const int bid = blockIdx.x;
    s[t] = (t < 196) ? bsum[t] : 0;
    __syncthreads();
    for (int d = 1; d < 256; d <<= 1) {
        const int u = (t >= d) ? s[t - d] : 0;
        __syncthreads();
        s[t] += u;
        __syncthreads();
    }
    const int myPre = (bid == 0) ? 0 : s[bid - 1];
    const int i = bid * 256 + t;
    if (i < N_NODES) {
        const int o = off[i] + myPre;
        off[i] = o;
        cur[i] = o;
    }
    if (bid == 0 && t == 0) off[N_NODES] = s[195];  // = E
}

// -------- Kernel 3: fused fill | wprep | xcast ------------------------------
// fill needs cur (post-scan); wprep/xcast are independent and overlap with it.
__global__ __launch_bounds__(256) void gnn_fill_xw(
    const int* __restrict__ ei, int* __restrict__ cur, int* __restrict__ srcs,
    const float* __restrict__ x, const float* __restrict__ Wl,
    const float* __restrict__ Wr, short* __restrict__ Wf,
    unsigned short* __restrict__ xbf, int full) {
    const int bid = blockIdx.x;
    const int t = threadIdx.x;
    if (bid < FILL_BLKS) {  // ---- bucket-fill src ids in dst order
        const int i = bid * 256 + t;
        const int stride = FILL_BLKS * 256;
        for (int e = i; e < E_EDGES; e += stride) {
            const int d = ei[E_EDGES + e];
            const int p = atomicAdd(&cur[d], 1);
            srcs[p] = ei[e];
        }
    } else if (bid < FILL_BLKS + WPREP_BLKS) {  // ---- W -> B-fragments
        const int tid = (bid - FILL_BLKS) * 256 + t;  // 0..4095
        const int lane = tid & 63;
        const int frag = tid >> 6;  // kstep*8 + ct
        const int kstep = frag >> 3;
        const int ct = frag & 7;
        const int kb = kstep * 32 + (lane >> 4) * 8;
        const int c = ct * 16 + (lane & 15);
        short8 v;
#pragma unroll
        for (int j = 0; j < 8; ++j) {
            const int k = kb + j;
            const float f = (k < F) ? Wl[k * F + c] : Wr[(k - F) * F + c];
            v[j] = (short)f2bf(f);
        }
        *reinterpret_cast<short8*>(Wf + (size_t)tid * 8) = v;
    } else {  // ---- x -> bf16 table (full path only)
        if (!full) return;
        const size_t i =
            ((size_t)(bid - FILL_BLKS - WPREP_BLKS) * 256 + t) * 8;
        const float4 a0 = *reinterpret_cast<const float4*>(x + i);
        const float4 a1 = *reinterpret_cast<const float4*>(x + i + 4);
        short8 v;
        v[0] = (short)f2bf(a0.x); v[1] = (short)f2bf(a0.y);
        v[2] = (short)f2bf(a0.z); v[3] = (short)f2bf(a0.w);
        v[4] = (short)f2bf(a1.x); v[5] = (short)f2bf(a1.y);
        v[6] = (short)f2bf(a1.z); v[7] = (short)f2bf(a1.w);
        *reinterpret_cast<short8*>((short*)xbf + i) = v;
    }
}

// -------- Kernel 4 (full): bf16 gather-aggregate, 16 lanes/row uint4 --------
// Wave per node. 4 lane-groups (16 lanes x 16B = one 256B row) take different
// neighbors: 4 rows per load instruction, 8 rows/iter via 2 independent
// accumulator sets. Cross-group combine: shfl_xor 16 + 32.
#define ACCQ(u, A0, A1)                                        \
    A0[0] += bfhi2f(u.x << 16); A0[1] += bfhi2f(u.x);          \
    A0[2] += bfhi2f(u.y << 16); A0[3] += bfhi2f(u.y);          \
    A1[0] += bfhi2f(u.z << 16); A1[1] += bfhi2f(u.z);          \
    A1[2] += bfhi2f(u.w << 16); A1[3] += bfhi2f(u.w);

__global__ __launch_bounds__(256) void gnn_aggregate_bf(
    const unsigned short* __restrict__ xbf, const int* __restrict__ off,
    const int* __restrict__ srcs, unsigned short* __restrict__ mbf) {
    const int node = blockIdx.x * 4 + (threadIdx.x >> 6);
    if (node >= N_NODES) return;
    const int lane = threadIdx.x & 63;
    const int grp = lane >> 4;   // which neighbor of the quad
    const int l16 = lane & 15;   // 16B column chunk within the row
    const int o0 = off[node];
    const int o1 = off[node + 1];
    const unsigned short* xb = xbf + l16 * 8;
    f32x4 a0 = {0.f, 0.f, 0.f, 0.f}, a1 = {0.f, 0.f, 0.f, 0.f};
    f32x4 b0 = {0.f, 0.f, 0.f, 0.f}, b1 = {0.f, 0.f, 0.f, 0.f};
    int j = o0;
    for (; j + 8 <= o1; j += 8) {
        const uint4 u =
            *reinterpret_cast<const uint4*>(xb + (size_t)srcs[j + grp] * F);
        const uint4 v =
            *reinterpret_cast<const uint4*>(xb + (size_t)srcs[j + 4 + grp] * F);
        ACCQ(u, a0, a1);
        ACCQ(v, b0, b1);
    }
    if (j + 4 <= o1) {
        const uint4 u =
            *reinterpret_cast<const uint4*>(xb + (size_t)srcs[j + grp] * F);
        ACCQ(u, a0, a1);
        j += 4;
    }
    if (j < o1) {  // 1-3 leftovers, predicated per lane-group
        const int jj = j + grp;
        const uint4 u = *reinterpret_cast<const uint4*>(
            xb + (size_t)srcs[(jj < o1) ? jj : o0] * F);
        if (jj < o1) { ACCQ(u, b0, b1); }
    }
    a0 += b0;
    a1 += b1;
    f32x4 t0, t1;
#pragma unroll
    for (int i = 0; i < 4; ++i) {
        t0[i] = __shfl_xor(a0[i], 16, 64);
        t1[i] = __shfl_xor(a1[i], 16, 64);
    }
    a0 += t0; a1 += t1;
#pragma unroll
    for (int i = 0; i < 4; ++i) {
        t0[i] = __shfl_xor(a0[i], 32, 64);
        t1[i] = __shfl_xor(a1[i], 32, 64);
    }
    a0 += t0; a1 += t1;
    if (grp == 0) {
        const float inv = 1.0f / (float)max(o1 - o0, 1);
        a0 *= inv; a1 *= inv;
        uint4 m;
        m.x = (unsigned)f2bf(a0[0]) | ((unsigned)f2bf(a0[1]) << 16);
        m.y = (unsigned)f2bf(a0[2]) | ((unsigned)f2bf(a0[3]) << 16);
        m.z = (unsigned)f2bf(a1[0]) | ((unsigned)f2bf(a1[1]) << 16);
        m.w = (unsigned)f2bf(a1[2]) | ((unsigned)f2bf(a1[3]) << 16);
        *reinterpret_cast<uint4*>(mbf + (size_t)node * F + l16 * 8) = m;
    }
}

// -------- Kernel 5 (full): MFMA finalize from bf16 tables ------------------
__global__ __launch_bounds__(256) void gnn_finalize_bf(
    const unsigned short* __restrict__ xbf, const unsigned short* __restrict__ mbf,
    const short* __restrict__ Wf, const float* __restrict__ bias,
    float* __restrict__ out) {
    const int t = threadIdx.x;
    const int lane = t & 63;
    const int wv = t >> 6;
    const int r0 = blockIdx.x * 64 + wv * 16;
    const int rl = lane & 15;
    const int kg = lane >> 4;
    const int arow = r0 + rl;
    const int arow_c = (arow < N_NODES) ? arow : (N_NODES - 1);

    f32x4 acc[8];
#pragma unroll
    for (int ct = 0; ct < 8; ++ct) acc[ct] = (f32x4){0.f, 0.f, 0.f, 0.f};

#pragma unroll
    for (int kstep = 0; kstep < 8; ++kstep) {
        const int k0 = kstep * 32 + kg * 8;
        const unsigned short* asrc =
            (kstep < 4) ? (mbf + (size_t)arow_c * F + k0)
                        : (xbf + (size_t)arow_c * F + (k0 - F));
        const short8 af = *reinterpret_cast<const short8*>(asrc);
#pragma unroll
        for (int ct = 0; ct < 8; ++ct) {
            const short8 bf = *reinterpret_cast<const short8*>(
                Wf + (size_t)((kstep * 8 + ct) * 64 + lane) * 8);
            acc[ct] = __builtin_amdgcn_mfma_f32_16x16x32_bf16(af, bf, acc[ct],
                                                              0, 0, 0);
        }
    }

#pragma unroll
    for (int ct = 0; ct < 8; ++ct) {
        const int c = ct * 16 + rl;
        const float bv = bias[c];
#pragma unroll
        for (int r = 0; r < 4; ++r) {
            const int row = r0 + kg * 4 + r;
            if (row < N_NODES)
                out[(size_t)row * F + c] = fmaxf(acc[ct][r] + bv, 0.0f);
        }
    }
}

// ======== fallback (round-9 proven) kernels: f32 gather via out ============
__global__ __launch_bounds__(256) void gnn_aggregate(
    const float* __restrict__ x, const int* __restrict__ off,
    const int* __restrict__ srcs, float* __restrict__ out) {
    const int node = blockIdx.x * 4 + (threadIdx.x >> 6);
    if (node >= N_NODES) return;
    const int lane = threadIdx.x & 63;
    const int half = lane >> 5;
    const int l32 = lane & 31;
    const int o0 = off[node];
    const int o1 = off[node + 1];
    f32x4 acc0 = {0.f, 0.f, 0.f, 0.f};
    f32x4 acc1 = {0.f, 0.f, 0.f, 0.f};
    int j = o0;
    for (; j + 4 <= o1; j += 4) {
        const int sA = srcs[j + half];
        const int sB = srcs[j + 2 + half];
        acc0 += *reinterpret_cast<const f32x4*>(x + (size_t)sA * F + l32 * 4);
        acc1 += *reinterpret_cast<const f32x4*>(x + (size_t)sB * F + l32 * 4);
    }
    for (; j < o1; j += 2) {
        const int jj = j + half;
        const int s = srcs[(jj < o1) ? jj : o0];
        f32x4 v = *reinterpret_cast<const f32x4*>(x + (size_t)s * F + l32 * 4);
        if (jj >= o1) v = (f32x4){0.f, 0.f, 0.f, 0.f};
        acc0 += v;
    }
    acc0 += acc1;
    f32x4 o;
    o[0] = __shfl_xor(acc0[0], 32, 64);
    o[1] = __shfl_xor(acc0[1], 32, 64);
    o[2] = __shfl_xor(acc0[2], 32, 64);
    o[3] = __shfl_xor(acc0[3], 32, 64);
    acc0 += o;
    if (half == 0) {
        const float inv = 1.0f / (float)max(o1 - o0, 1);
        acc0 *= inv;
        *reinterpret_cast<f32x4*>(out + (size_t)node * F + l32 * 4) = acc0;
    }
}

__global__ __launch_bounds__(256) void gnn_finalize_mfma(
    const float* __restrict__ x, const short* __restrict__ Wf,
    const float* __restrict__ bias, float* __restrict__ out) {
    const int t = threadIdx.x;
    const int lane = t & 63;
    const int wv = t >> 6;
    const int r0 = blockIdx.x * 64 + wv * 16;
    const int rl = lane & 15;
    const int kg = lane >> 4;
    const int arow = r0 + rl;
    const int arow_c = (arow < N_NODES) ? arow : (N_NODES - 1);
    f32x4 acc[8];
#pragma unroll
    for (int ct = 0; ct < 8; ++ct) acc[ct] = (f32x4){0.f, 0.f, 0.f, 0.f};
#pragma unroll
    for (int kstep = 0; kstep < 8; ++kstep) {
        const int k0 = kstep * 32 + kg * 8;
        const float* asrc = (kstep < 4) ? (out + (size_t)arow_c * F + k0)
                                        : (x + (size_t)arow_c * F + (k0 - F));
        const float4 a0 = *reinterpret_cast<const float4*>(asrc);
        const float4 a1 = *reinterpret_cast<const float4*>(asrc + 4);
        short8 af;
        af[0] = (short)f2bf(a0.x); af[1] = (short)f2bf(a0.y);
        af[2] = (short)f2bf(a0.z); af[3] = (short)f2bf(a0.w);
        af[4] = (short)f2bf(a1.x); af[5] = (short)f2bf(a1.y);
        af[6] = (short)f2bf(a1.z); af[7] = (short)f2bf(a1.w);
#pragma unroll
        for (int ct = 0; ct < 8; ++ct) {
            const short8 bf = *reinterpret_cast<const short8*>(
                Wf + (size_t)((kstep * 8 + ct) * 64 + lane) * 8);
            acc[ct] = __builtin_amdgcn_mfma_f32_16x16x32_bf16(af, bf, acc[ct],
                                                              0, 0, 0);
        }
    }
#pragma unroll
    for (int ct = 0; ct < 8; ++ct) {
        const int c = ct * 16 + rl;
        const float bv = bias[c];
#pragma unroll
        for (int r = 0; r < 4; ++r) {
            const int row = r0 + kg * 4 + r;
            if (row < N_NODES)
                out[(size_t)row * F + c] = fmaxf(acc[ct][r] + bv, 0.0f);
        }
    }
}

extern "C" void kernel_launch(void* const* d_in, const int* in_sizes, int n_in,
                              void* d_out, int out_size, void* d_ws,
                              size_t ws_size, hipStream_t stream) {
    const float* x = (const float*)d_in[0];
    const int* ei = (const int*)d_in[1];
    const float* Wl = (const float*)d_in[2];
    const float* Wr = (const float*)d_in[3];
    const float* b = (const float*)d_in[4];
    float* out = (float*)d_out;

    char* ws = (char*)d_ws;
    int* deg = (int*)(ws + DEG_OFF);
    int* off = (int*)(ws + OFF_OFF);
    int* cur = (int*)(ws + CUR_OFF);
    int* bsum = (int*)(ws + BSUM_OFF);
    short* Wf = (short*)(ws + WF_OFF);
    int* srcs = (int*)(ws + SRC_OFF);
    unsigned short* xbf = (unsigned short*)(ws + XBF_OFF);
    unsigned short* mbf = (unsigned short*)(ws + MBF_OFF);

    const int full = (ws_size >= WS_NEED_FULL) ? 1 : 0;

    hipMemsetAsync(deg, 0, N_NODES * sizeof(int), stream);
    gnn_hist<<<2048, 256, 0, stream>>>(ei, deg);
    gnn_scan_a<<<196, 256, 0, stream>>>(deg, off, bsum);
    gnn_scan2<<<196, 256, 0, stream>>>(bsum, off, cur);
    gnn_fill_xw<<<FXW_GRID, 256, 0, stream>>>(ei, cur, srcs, x, Wl, Wr, Wf,
                                              xbf, full);

    if (full) {
        gnn_aggregate_bf<<<(N_NODES + 3) / 4, 256, 0, stream>>>(xbf, off, srcs,
                                                                mbf);
        gnn_finalize_bf<<<(N_NODES + 63) / 64, 256, 0, stream>>>(xbf, mbf, Wf,
                                                                 b, out);
    } else {
        gnn_aggregate<<<(N_NODES + 3) / 4, 256, 0, stream>>>(x, off, srcs, out);
        gnn_finalize_mfma<<<(N_NODES + 63) / 64, 256, 0, stream>>>(x, Wf, b,
                                                                   out);
    }
}

// Round 14
// 192.500 us; speedup vs baseline: 1.0440x; 1.0440x over previous
//
#include <hip/hip_runtime.h>

#define N_NODES 50000
#define E_EDGES 640000
#define F 128
#define NXCD 8
#define NPER (N_NODES / NXCD)  // 6250

typedef __attribute__((ext_vector_type(8))) short short8;
typedef __attribute__((ext_vector_type(4))) float f32x4;

// -------- workspace layout (bytes) --------
#define DEG_OFF 0            // N int32
#define OFF_OFF 200704       // N+1 int32
#define CUR_OFF 401408       // N int32
#define BSUM_OFF 601600      // 196 int32
#define WF_OFF 603648        // 32768 bf16 (64 KB) W fragments
#define SRC_OFF 734720       // E uint16 (1.28 MB) -> ends 2,014,720
#define XBF_OFF 3294720      // N*F bf16 (12.8 MB)
#define MBF_OFF 16094720     // N*F bf16 (12.8 MB)
#define WS_NEED_FULL 28894720ULL

// prep kernel block ranges (hist | wprep | xcast fused; round-12 proven)
#define XCAST_BLKS 3125      // 3125*256*8 == N*F exactly
#define WPREP_BLKS 16
#define HIST_BLKS 2048
#define PREP_GRID (XCAST_BLKS + WPREP_BLKS + HIST_BLKS)
#define FILL_BLKS 2048       // 8 XCD groups x 256 blocks

__device__ __forceinline__ unsigned short f2bf(float f) {
    unsigned int u = __builtin_bit_cast(unsigned int, f);
    u += 0x7FFFu + ((u >> 16) & 1u);  // round-to-nearest-even
    return (unsigned short)(u >> 16);
}
__device__ __forceinline__ float bfhi2f(unsigned int hi16) {  // bits 31:16
    return __builtin_bit_cast(float, hi16 & 0xFFFF0000u);
}

// -------- Kernel 1: fused prep = xcast | wprep | hist (independent work) ----
__global__ __launch_bounds__(256) void gnn_prep(
    const float* __restrict__ x, const int* __restrict__ ei,
    const float* __restrict__ Wl, const float* __restrict__ Wr,
    short* __restrict__ Wf, unsigned short* __restrict__ xbf,
    int* __restrict__ deg, int full) {
    const int bid = blockIdx.x;
    const int t = threadIdx.x;
    if (bid < XCAST_BLKS) {  // ---- x -> bf16 table
        if (!full) return;
        const size_t i = ((size_t)bid * 256 + t) * 8;
        const float4 a0 = *reinterpret_cast<const float4*>(x + i);
        const float4 a1 = *reinterpret_cast<const float4*>(x + i + 4);
        short8 v;
        v[0] = (short)f2bf(a0.x); v[1] = (short)f2bf(a0.y);
        v[2] = (short)f2bf(a0.z); v[3] = (short)f2bf(a0.w);
        v[4] = (short)f2bf(a1.x); v[5] = (short)f2bf(a1.y);
        v[6] = (short)f2bf(a1.z); v[7] = (short)f2bf(a1.w);
        *reinterpret_cast<short8*>((short*)xbf + i) = v;
    } else if (bid < XCAST_BLKS + WPREP_BLKS) {  // ---- W -> B-fragments
        const int tid = (bid - XCAST_BLKS) * 256 + t;  // 0..4095
        const int lane = tid & 63;
        const int frag = tid >> 6;  // kstep*8 + ct
        const int kstep = frag >> 3;
        const int ct = frag & 7;
        const int kb = kstep * 32 + (lane >> 4) * 8;
        const int c = ct * 16 + (lane & 15);
        short8 v;
#pragma unroll
        for (int j = 0; j < 8; ++j) {
            const int k = kb + j;
            const float f = (k < F) ? Wl[k * F + c] : Wr[(k - F) * F + c];
            v[j] = (short)f2bf(f);
        }
        *reinterpret_cast<short8*>(Wf + (size_t)tid * 8) = v;
    } else {  // ---- in-degree histogram
        const int i = (bid - XCAST_BLKS - WPREP_BLKS) * 256 + t;
        const int stride = HIST_BLKS * 256;
        for (int e = i; e < E_EDGES; e += stride)
            atomicAdd(&deg[ei[E_EDGES + e]], 1);
    }
}

// -------- Kernel 2a: per-block local scan (196 blocks x 256) --------
__global__ __launch_bounds__(256) void gnn_scan_a(const int* __restrict__ deg,
                                                  int* __restrict__ off,
                                                  int* __restrict__ bsum) {
    __shared__ int s[256];
    const int t = threadIdx.x;
    const int i = blockIdx.x * 256 + t;
    const int v = (i < N_NODES) ? deg[i] : 0;
    s[t] = v;
    __syncthreads();
    for (int d = 1; d < 256; d <<= 1) {
        const int u = (t >= d) ? s[t - d] : 0;
        __syncthreads();
        s[t] += u;
        __syncthreads();
    }
    if (i < N_NODES) off[i] = s[t] - v;
    if (t == 255) bsum[blockIdx.x] = s[255];
}

// -------- Kernel 2b: merged scan-of-sums + apply (196 blocks) --------
__global__ __launch_bounds__(256) void gnn_scan2(const int* __restrict__ bsum,
                                                 int* __restrict__ off,
                                                 int* __restrict__ cur) {
    __shared__ int s[256];
    const int t = threadIdx.x;
    const int bid = blockIdx.x;
    s[t] = (t < 196) ? bsum[t] : 0;
    __syncthreads();
    for (int d = 1; d < 256; d <<= 1) {
        const int u = (t >= d) ? s[t - d] : 0;
        __syncthreads();
        s[t] += u;
        __syncthreads();
    }
    const int myPre = (bid == 0) ? 0 : s[bid - 1];
    const int i = bid * 256 + t;
    if (i < N_NODES) {
        const int o = off[i] + myPre;
        off[i] = o;
        cur[i] = o;
    }
    if (bid == 0 && t == 0) off[N_NODES] = s[195];  // = E
}

// -------- Kernel 3: XCD-ownership bucket-fill (u16 srcs) --------------------
// 8 groups of 256 blocks; group g owns dst range [g*NPER,(g+1)*NPER).
// Each group scans ALL dst (coalesced, LLC-broadcast) and fills only its own
// range -> every srcs cache line is written by one XCD only (no L2 bouncing).
__global__ __launch_bounds__(256) void gnn_fill(
    const int* __restrict__ ei, int* __restrict__ cur,
    unsigned short* __restrict__ srcs) {
    const int grp = blockIdx.x & (NXCD - 1);      // XCD heuristic: bid % 8
    const int g = blockIdx.x >> 3;                // 0..255 within group
    const int lo = grp * NPER;
    const int hi = lo + NPER;
    const int i = g * 256 + threadIdx.x;
    const int stride = (FILL_BLKS / NXCD) * 256;  // 65536
    for (int e = i; e < E_EDGES; e += stride) {
        const int d = ei[E_EDGES + e];
        if (d >= lo && d < hi) {
            const int p = atomicAdd(&cur[d], 1);
            srcs[p] = (unsigned short)ei[e];
        }
    }
}

// -------- Kernel 4 (full): bf16 gather-aggregate, 16 lanes/row uint4 --------
#define ACCQ(u, A0, A1)                                        \
    A0[0] += bfhi2f(u.x << 16); A0[1] += bfhi2f(u.x);          \
    A0[2] += bfhi2f(u.y << 16); A0[3] += bfhi2f(u.y);          \
    A1[0] += bfhi2f(u.z << 16); A1[1] += bfhi2f(u.z);          \
    A1[2] += bfhi2f(u.w << 16); A1[3] += bfhi2f(u.w);

__global__ __launch_bounds__(256) void gnn_aggregate_bf(
    const unsigned short* __restrict__ xbf, const int* __restrict__ off,
    const unsigned short* __restrict__ srcs, unsigned short* __restrict__ mbf) {
    const int node = blockIdx.x * 4 + (threadIdx.x >> 6);
    if (node >= N_NODES) return;
    const int lane = threadIdx.x & 63;
    const int grp = lane >> 4;   // which neighbor of the quad
    const int l16 = lane & 15;   // 16B column chunk within the row
    const int o0 = off[node];
    const int o1 = off[node + 1];
    const unsigned short* xb = xbf + l16 * 8;
    f32x4 a0 = {0.f, 0.f, 0.f, 0.f}, a1 = {0.f, 0.f, 0.f, 0.f};
    f32x4 b0 = {0.f, 0.f, 0.f, 0.f}, b1 = {0.f, 0.f, 0.f, 0.f};
    int j = o0;
    for (; j + 8 <= o1; j += 8) {
        const uint4 u = *reinterpret_cast<const uint4*>(
            xb + (size_t)srcs[j + grp] * F);
        const uint4 v = *reinterpret_cast<const uint4*>(
            xb + (size_t)srcs[j + 4 + grp] * F);
        ACCQ(u, a0, a1);
        ACCQ(v, b0, b1);
    }
    if (j + 4 <= o1) {
        const uint4 u = *reinterpret_cast<const uint4*>(
            xb + (size_t)srcs[j + grp] * F);
        ACCQ(u, a0, a1);
        j += 4;
    }
    if (j < o1) {  // 1-3 leftovers, predicated per lane-group
        const int jj = j + grp;
        const uint4 u = *reinterpret_cast<const uint4*>(
            xb + (size_t)srcs[(jj < o1) ? jj : o0] * F);
        if (jj < o1) { ACCQ(u, b0, b1); }
    }
    a0 += b0;
    a1 += b1;
    f32x4 t0, t1;
#pragma unroll
    for (int i = 0; i < 4; ++i) {
        t0[i] = __shfl_xor(a0[i], 16, 64);
        t1[i] = __shfl_xor(a1[i], 16, 64);
    }
    a0 += t0; a1 += t1;
#pragma unroll
    for (int i = 0; i < 4; ++i) {
        t0[i] = __shfl_xor(a0[i], 32, 64);
        t1[i] = __shfl_xor(a1[i], 32, 64);
    }
    a0 += t0; a1 += t1;
    if (grp == 0) {
        const float inv = 1.0f / (float)max(o1 - o0, 1);
        a0 *= inv; a1 *= inv;
        uint4 m;
        m.x = (unsigned)f2bf(a0[0]) | ((unsigned)f2bf(a0[1]) << 16);
        m.y = (unsigned)f2bf(a0[2]) | ((unsigned)f2bf(a0[3]) << 16);
        m.z = (unsigned)f2bf(a1[0]) | ((unsigned)f2bf(a1[1]) << 16);
        m.w = (unsigned)f2bf(a1[2]) | ((unsigned)f2bf(a1[3]) << 16);
        *reinterpret_cast<uint4*>(mbf + (size_t)node * F + l16 * 8) = m;
    }
}

// -------- Kernel 5 (full): MFMA finalize from bf16 tables ------------------
__global__ __launch_bounds__(256) void gnn_finalize_bf(
    const unsigned short* __restrict__ xbf, const unsigned short* __restrict__ mbf,
    const short* __restrict__ Wf, const float* __restrict__ bias,
    float* __restrict__ out) {
    const int t = threadIdx.x;
    const int lane = t & 63;
    const int wv = t >> 6;
    const int r0 = blockIdx.x * 64 + wv * 16;
    const int rl = lane & 15;
    const int kg = lane >> 4;
    const int arow = r0 + rl;
    const int arow_c = (arow < N_NODES) ? arow : (N_NODES - 1);

    f32x4 acc[8];
#pragma unroll
    for (int ct = 0; ct < 8; ++ct) acc[ct] = (f32x4){0.f, 0.f, 0.f, 0.f};

#pragma unroll
    for (int kstep = 0; kstep < 8; ++kstep) {
        const int k0 = kstep * 32 + kg * 8;
        const unsigned short* asrc =
            (kstep < 4) ? (mbf + (size_t)arow_c * F + k0)
                        : (xbf + (size_t)arow_c * F + (k0 - F));
        const short8 af = *reinterpret_cast<const short8*>(asrc);
#pragma unroll
        for (int ct = 0; ct < 8; ++ct) {
            const short8 bf = *reinterpret_cast<const short8*>(
                Wf + (size_t)((kstep * 8 + ct) * 64 + lane) * 8);
            acc[ct] = __builtin_amdgcn_mfma_f32_16x16x32_bf16(af, bf, acc[ct],
                                                              0, 0, 0);
        }
    }

#pragma unroll
    for (int ct = 0; ct < 8; ++ct) {
        const int c = ct * 16 + rl;
        const float bv = bias[c];
#pragma unroll
        for (int r = 0; r < 4; ++r) {
            const int row = r0 + kg * 4 + r;
            if (row < N_NODES)
                out[(size_t)row * F + c] = fmaxf(acc[ct][r] + bv, 0.0f);
        }
    }
}

// ======== fallback (round-9 proven) kernels: f32 gather via out ============
__global__ __launch_bounds__(256) void gnn_aggregate(
    const float* __restrict__ x, const int* __restrict__ off,
    const unsigned short* __restrict__ srcs, float* __restrict__ out) {
    const int node = blockIdx.x * 4 + (threadIdx.x >> 6);
    if (node >= N_NODES) return;
    const int lane = threadIdx.x & 63;
    const int half = lane >> 5;
    const int l32 = lane & 31;
    const int o0 = off[node];
    const int o1 = off[node + 1];
    f32x4 acc0 = {0.f, 0.f, 0.f, 0.f};
    f32x4 acc1 = {0.f, 0.f, 0.f, 0.f};
    int j = o0;
    for (; j + 4 <= o1; j += 4) {
        const int sA = srcs[j + half];
        const int sB = srcs[j + 2 + half];
        acc0 += *reinterpret_cast<const f32x4*>(x + (size_t)sA * F + l32 * 4);
        acc1 += *reinterpret_cast<const f32x4*>(x + (size_t)sB * F + l32 * 4);
    }
    for (; j < o1; j += 2) {
        const int jj = j + half;
        const int s = srcs[(jj < o1) ? jj : o0];
        f32x4 v = *reinterpret_cast<const f32x4*>(x + (size_t)s * F + l32 * 4);
        if (jj >= o1) v = (f32x4){0.f, 0.f, 0.f, 0.f};
        acc0 += v;
    }
    acc0 += acc1;
    f32x4 o;
    o[0] = __shfl_xor(acc0[0], 32, 64);
    o[1] = __shfl_xor(acc0[1], 32, 64);
    o[2] = __shfl_xor(acc0[2], 32, 64);
    o[3] = __shfl_xor(acc0[3], 32, 64);
    acc0 += o;
    if (half == 0) {
        const float inv = 1.0f / (float)max(o1 - o0, 1);
        acc0 *= inv;
        *reinterpret_cast<f32x4*>(out + (size_t)node * F + l32 * 4) = acc0;
    }
}

__global__ __launch_bounds__(256) void gnn_finalize_mfma(
    const float* __restrict__ x, const short* __restrict__ Wf,
    const float* __restrict__ bias, float* __restrict__ out) {
    const int t = threadIdx.x;
    const int lane = t & 63;
    const int wv = t >> 6;
    const int r0 = blockIdx.x * 64 + wv * 16;
    const int rl = lane & 15;
    const int kg = lane >> 4;
    const int arow = r0 + rl;
    const int arow_c = (arow < N_NODES) ? arow : (N_NODES - 1);
    f32x4 acc[8];
#pragma unroll
    for (int ct = 0; ct < 8; ++ct) acc[ct] = (f32x4){0.f, 0.f, 0.f, 0.f};
#pragma unroll
    for (int kstep = 0; kstep < 8; ++kstep) {
        const int k0 = kstep * 32 + kg * 8;
        const float* asrc = (kstep < 4) ? (out + (size_t)arow_c * F + k0)
                                        : (x + (size_t)arow_c * F + (k0 - F));
        const float4 a0 = *reinterpret_cast<const float4*>(asrc);
        const float4 a1 = *reinterpret_cast<const float4*>(asrc + 4);
        short8 af;
        af[0] = (short)f2bf(a0.x); af[1] = (short)f2bf(a0.y);
        af[2] = (short)f2bf(a0.z); af[3] = (short)f2bf(a0.w);
        af[4] = (short)f2bf(a1.x); af[5] = (short)f2bf(a1.y);
        af[6] = (short)f2bf(a1.z); af[7] = (short)f2bf(a1.w);
#pragma unroll
        for (int ct = 0; ct < 8; ++ct) {
            const short8 bf = *reinterpret_cast<const short8*>(
                Wf + (size_t)((kstep * 8 + ct) * 64 + lane) * 8);
            acc[ct] = __builtin_amdgcn_mfma_f32_16x16x32_bf16(af, bf, acc[ct],
                                                              0, 0, 0);
        }
    }
#pragma unroll
    for (int ct = 0; ct < 8; ++ct) {
        const int c = ct * 16 + rl;
        const float bv = bias[c];
#pragma unroll
        for (int r = 0; r < 4; ++r) {
            const int row = r0 + kg * 4 + r;
            if (row < N_NODES)
                out[(size_t)row * F + c] = fmaxf(acc[ct][r] + bv, 0.0f);
        }
    }
}

extern "C" void kernel_launch(void* const* d_in, const int* in_sizes, int n_in,
                              void* d_out, int out_size, void* d_ws,
                              size_t ws_size, hipStream_t stream) {
    const float* x = (const float*)d_in[0];
    const int* ei = (const int*)d_in[1];
    const float* Wl = (const float*)d_in[2];
    const float* Wr = (const float*)d_in[3];
    const float* b = (const float*)d_in[4];
    float* out = (float*)d_out;

    char* ws = (char*)d_ws;
    int* deg = (int*)(ws + DEG_OFF);
    int* off = (int*)(ws + OFF_OFF);
    int* cur = (int*)(ws + CUR_OFF);
    int* bsum = (int*)(ws + BSUM_OFF);
    short* Wf = (short*)(ws + WF_OFF);
    unsigned short* srcs = (unsigned short*)(ws + SRC_OFF);
    unsigned short* xbf = (unsigned short*)(ws + XBF_OFF);
    unsigned short* mbf = (unsigned short*)(ws + MBF_OFF);

    const int full = (ws_size >= WS_NEED_FULL) ? 1 : 0;

    hipMemsetAsync(deg, 0, N_NODES * sizeof(int), stream);
    gnn_prep<<<PREP_GRID, 256, 0, stream>>>(x, ei, Wl, Wr, Wf, xbf, deg, full);
    gnn_scan_a<<<196, 256, 0, stream>>>(deg, off, bsum);
    gnn_scan2<<<196, 256, 0, stream>>>(bsum, off, cur);
    gnn_fill<<<FILL_BLKS, 256, 0, stream>>>(ei, cur, srcs);

    if (full) {
        gnn_aggregate_bf<<<(N_NODES + 3) / 4, 256, 0, stream>>>(xbf, off, srcs,
                                                                mbf);
        gnn_finalize_bf<<<(N_NODES + 63) / 64, 256, 0, stream>>>(xbf, mbf, Wf,
                                                                 b, out);
    } else {
        gnn_aggregate<<<(N_NODES + 3) / 4, 256, 0, stream>>>(x, off, srcs, out);
        gnn_finalize_mfma<<<(N_NODES + 63) / 64, 256, 0, stream>>>(x, Wf, b,
                                                                   out);
    }
}